// Round 1
// baseline (275.467 us; speedup 1.0000x reference)
//
#include <hip/hip_runtime.h>
#include <hip/hip_bf16.h>
#include <stdint.h>

// Problem constants (B=4, N=1024, F=1024, H=16, D=64)
#define FDIM 1024
#define NHEADS 16
#define HDIM 64
#define BATCH 4
#define SEQ 1024
#define MROWS (BATCH*SEQ)   // 4096

typedef short bf16x8 __attribute__((ext_vector_type(8)));
typedef float f32x4 __attribute__((ext_vector_type(4)));

__device__ inline unsigned short f2bf(float f){
  union { float f; uint32_t u; } v; v.f = f;
  uint32_t u = v.u;
  uint32_t r = (u + 0x7fffu + ((u >> 16) & 1u)) >> 16;
  return (unsigned short)r;
}

__device__ inline void gld_lds16(const void* g, void* l){
  __builtin_amdgcn_global_load_lds((const __attribute__((address_space(1))) uint32_t*)g,
                                   (__attribute__((address_space(3))) uint32_t*)l, 16, 0, 0);
}

// ---------------- weight fp32 -> bf16 ----------------
__global__ __launch_bounds__(256) void cvt_w(const float* __restrict__ src,
                                             unsigned short* __restrict__ dst, int n4){
  int i = blockIdx.x*256 + threadIdx.x;
  if (i < n4){
    float4 v = ((const float4*)src)[i];
    ushort4 o; o.x=f2bf(v.x); o.y=f2bf(v.y); o.z=f2bf(v.z); o.w=f2bf(v.w);
    ((ushort4*)dst)[i] = o;
  }
}

// ---------------- LayerNorm + pos add ----------------
__global__ __launch_bounds__(256) void ln_posadd(const float* __restrict__ x,
                                                 const float* __restrict__ pos,
                                                 const float* __restrict__ g,
                                                 const float* __restrict__ be,
                                                 unsigned short* __restrict__ normb,
                                                 unsigned short* __restrict__ posnb){
  int row = blockIdx.x, t = threadIdx.x;
  float4 v = ((const float4*)(x + (size_t)row*FDIM))[t];
  float s  = v.x+v.y+v.z+v.w;
  float sq = v.x*v.x+v.y*v.y+v.z*v.z+v.w*v.w;
  #pragma unroll
  for (int off=32; off>=1; off>>=1){ s += __shfl_down(s,off); sq += __shfl_down(sq,off); }
  __shared__ float red[8];
  int w=t>>6, lane=t&63;
  if (!lane){ red[w]=s; red[4+w]=sq; }
  __syncthreads();
  s  = red[0]+red[1]+red[2]+red[3];
  sq = red[4]+red[5]+red[6]+red[7];
  float mu  = s*(1.0f/FDIM);
  float var = sq*(1.0f/FDIM) - mu*mu;
  float rs  = rsqrtf(var + 1e-5f);
  float4 gg=((const float4*)g)[t], bb=((const float4*)be)[t];
  float4 pp=((const float4*)(pos + (size_t)row*FDIM))[t];
  float n0=(v.x-mu)*rs*gg.x+bb.x, n1=(v.y-mu)*rs*gg.y+bb.y;
  float n2=(v.z-mu)*rs*gg.z+bb.z, n3=(v.w-mu)*rs*gg.w+bb.w;
  ushort4 nb; nb.x=f2bf(n0); nb.y=f2bf(n1); nb.z=f2bf(n2); nb.w=f2bf(n3);
  ushort4 pb; pb.x=f2bf(n0+pp.x); pb.y=f2bf(n1+pp.y); pb.z=f2bf(n2+pp.z); pb.w=f2bf(n3+pp.w);
  ((ushort4*)(normb+(size_t)row*FDIM))[t]=nb;
  ((ushort4*)(posnb+(size_t)row*FDIM))[t]=pb;
}

// ---------------- GEMM: C[M,N] = A[M,K] @ W[N,K]^T + bias ----------------
// MODE 0: store bf16 into Cout. MODE 1: fp32 store of acc + bias + resid.
template<int MODE>
__global__ __launch_bounds__(256) void gemm_bt(const unsigned short* __restrict__ A,
                                               const unsigned short* __restrict__ Bw,
                                               const float* __restrict__ bias,
                                               const float* __restrict__ resid,
                                               void* __restrict__ Cout,
                                               int M, int Nout, int K){
  __shared__ unsigned short Als[128*32];
  __shared__ unsigned short Bls[128*32];
  int t = threadIdx.x, w = t>>6, lane = t&63;
  int m0 = blockIdx.x*128, n0 = blockIdx.y*128;
  int wm = (w>>1)*64, wn = (w&1)*64;
  int lrow = lane&15, lk = (lane>>4)*8, rg = lane>>4;
  f32x4 acc[4][4] = {};
  for (int k0=0; k0<K; k0+=32){
    #pragma unroll
    for (int i=0;i<2;i++){
      int c = t + i*256;
      gld_lds16(A  + (size_t)(m0 + (c>>2))*K + k0 + (c&3)*8, Als + c*8);
      gld_lds16(Bw + (size_t)(n0 + (c>>2))*K + k0 + (c&3)*8, Bls + c*8);
    }
    __syncthreads();
    bf16x8 a[4], b[4];
    #pragma unroll
    for (int i=0;i<4;i++){
      a[i] = *(const bf16x8*)&Als[(wm + i*16 + lrow)*32 + lk];
      b[i] = *(const bf16x8*)&Bls[(wn + i*16 + lrow)*32 + lk];
    }
    #pragma unroll
    for (int mi=0;mi<4;mi++)
      #pragma unroll
      for (int ni=0;ni<4;ni++)
        acc[mi][ni] = __builtin_amdgcn_mfma_f32_16x16x32_bf16(a[mi], b[ni], acc[mi][ni], 0,0,0);
    __syncthreads();
  }
  #pragma unroll
  for (int mi=0;mi<4;mi++){
    #pragma unroll
    for (int ni=0;ni<4;ni++){
      int n = n0 + wn + ni*16 + lrow;
      float bs = bias[n];
      #pragma unroll
      for (int r=0;r<4;r++){
        int m = m0 + wm + mi*16 + rg*4 + r;
        float vv = acc[mi][ni][r] + bs;
        size_t idx = (size_t)m*Nout + n;
        if (MODE==0) ((unsigned short*)Cout)[idx] = f2bf(vv);
        else         ((float*)Cout)[idx] = vv + resid[idx];
      }
    }
  }
}

// ---------------- Flash attention: block = (b, h, 64 q-rows) ----------------
// qk layout: [B*N, 2F] bf16 (cols 0..F-1 = Q, F..2F-1 = K), heads are 64-col slices
// vbuf:      [B*N, F] bf16
// wvbuf out: [B*N, F] bf16
__global__ __launch_bounds__(256) void attn(const unsigned short* __restrict__ qk,
                                            const unsigned short* __restrict__ vbuf,
                                            unsigned short* __restrict__ wvbuf){
  __shared__ unsigned short Qls[64*64];
  __shared__ unsigned short Kls[64*64];
  __shared__ unsigned short Vtls[64*64];   // transposed: [d][key]
  __shared__ unsigned short Pls[64*64];
  int t=threadIdx.x, w=t>>6, lane=t&63;
  int lrow=lane&15, lk=(lane>>4)*8, rg=lane>>4;
  int q0=blockIdx.x*64, h=blockIdx.y, b=blockIdx.z;
  const size_t qs = 2*FDIM;
  // stage Q once
  #pragma unroll
  for (int i=0;i<2;i++){
    int c=t+i*256;
    gld_lds16(qk + (size_t)(b*SEQ + q0 + (c>>3))*qs + h*HDIM + (c&7)*8, Qls + c*8);
  }
  f32x4 o[4] = {};
  float m_run[4], l_run[4];
  #pragma unroll
  for (int r=0;r<4;r++){ m_run[r]=-1e30f; l_run[r]=0.f; }
  __syncthreads();
  bf16x8 qa[2];
  qa[0] = *(const bf16x8*)&Qls[(w*16+lrow)*64 + lk];
  qa[1] = *(const bf16x8*)&Qls[(w*16+lrow)*64 + 32 + lk];

  for (int kt=0; kt<16; ++kt){
    int key0 = kt*64;
    __syncthreads();  // previous iteration's LDS reads complete
    #pragma unroll
    for (int i=0;i<2;i++){
      int c=t+i*256;
      gld_lds16(qk + (size_t)(b*SEQ + key0 + (c>>3))*qs + FDIM + h*HDIM + (c&7)*8, Kls + c*8);
    }
    #pragma unroll
    for (int i=0;i<2;i++){
      int c=t+i*256;
      int key=c&63, d0=(c>>6)*8;
      bf16x8 vv = *(const bf16x8*)(vbuf + (size_t)(b*SEQ + key0 + key)*FDIM + h*HDIM + d0);
      #pragma unroll
      for (int j=0;j<8;j++) Vtls[(d0+j)*64 + key] = (unsigned short)vv[j];
    }
    __syncthreads();
    // S = Q K^T (per wave: 16 q-rows x 64 keys)
    f32x4 s[4] = {};
    #pragma unroll
    for (int kf=0; kf<2; kf++){
      #pragma unroll
      for (int ni=0;ni<4;ni++){
        bf16x8 kb = *(const bf16x8*)&Kls[(ni*16+lrow)*64 + kf*32 + lk];
        s[ni] = __builtin_amdgcn_mfma_f32_16x16x32_bf16(qa[kf], kb, s[ni], 0,0,0);
      }
    }
    // online softmax; acc mapping: q_local = rg*4+r, key_local = ni*16 + (lane&15)
    #pragma unroll
    for (int r=0;r<4;r++){
      float tm = fmaxf(fmaxf(s[0][r],s[1][r]), fmaxf(s[2][r],s[3][r])) * 0.125f;
      #pragma unroll
      for (int off=1; off<16; off<<=1) tm = fmaxf(tm, __shfl_xor(tm, off));
      float mn = fmaxf(m_run[r], tm);
      float sc = __expf(m_run[r] - mn);
      float p[4]; float ts = 0.f;
      #pragma unroll
      for (int ni=0;ni<4;ni++){ p[ni] = __expf(s[ni][r]*0.125f - mn); ts += p[ni]; }
      #pragma unroll
      for (int off=1; off<16; off<<=1) ts += __shfl_xor(ts, off);
      l_run[r] = l_run[r]*sc + ts;
      m_run[r] = mn;
      #pragma unroll
      for (int nd=0;nd<4;nd++) o[nd][r] *= sc;
      #pragma unroll
      for (int ni=0;ni<4;ni++) Pls[(w*16 + rg*4 + r)*64 + ni*16 + lrow] = f2bf(p[ni]);
    }
    asm volatile("s_waitcnt lgkmcnt(0)" ::: "memory");
    // O += P V   (P: [16 q x 64 key], V^T in LDS: [d][key])
    #pragma unroll
    for (int kf=0; kf<2; kf++){
      bf16x8 pa = *(const bf16x8*)&Pls[(w*16+lrow)*64 + kf*32 + lk];
      #pragma unroll
      for (int nd=0;nd<4;nd++){
        bf16x8 vb = *(const bf16x8*)&Vtls[(nd*16+lrow)*64 + kf*32 + lk];
        o[nd] = __builtin_amdgcn_mfma_f32_16x16x32_bf16(pa, vb, o[nd], 0,0,0);
      }
    }
  }
  // epilogue: divide by softmax denom, store bf16
  #pragma unroll
  for (int nd=0; nd<4; nd++){
    #pragma unroll
    for (int r=0;r<4;r++){
      float val = o[nd][r] / l_run[r];
      wvbuf[(size_t)(b*SEQ + q0 + w*16 + rg*4 + r)*FDIM + h*HDIM + nd*16 + lrow] = f2bf(val);
    }
  }
}

extern "C" void kernel_launch(void* const* d_in, const int* in_sizes, int n_in,
                              void* d_out, int out_size, void* d_ws, size_t ws_size,
                              hipStream_t stream) {
  const float* in_feats = (const float*)d_in[0];
  const float* pos      = (const float*)d_in[1];
  const float* ln_g     = (const float*)d_in[2];
  const float* ln_b     = (const float*)d_in[3];
  const float* w_qk     = (const float*)d_in[4];
  const float* b_qk     = (const float*)d_in[5];
  const float* w_v      = (const float*)d_in[6];
  const float* b_v      = (const float*)d_in[7];
  const float* w_o      = (const float*)d_in[8];
  const float* b_o      = (const float*)d_in[9];
  float* out = (float*)d_out;

  char* ws = (char*)d_ws;
  // workspace layout (bytes)
  unsigned short* norm_b = (unsigned short*)(ws + 0);              // 4096*1024*2 = 8 MiB
  unsigned short* posn_b = (unsigned short*)(ws + (8u<<20));       // 8 MiB
  unsigned short* wqk_b  = (unsigned short*)(ws + (16u<<20));      // 4 MiB
  unsigned short* wv_b   = (unsigned short*)(ws + (20u<<20));      // 2 MiB
  unsigned short* wo_b   = (unsigned short*)(ws + (22u<<20));      // 2 MiB
  unsigned short* qk_buf = (unsigned short*)(ws + (24u<<20));      // 4096*2048*2 = 16 MiB
  unsigned short* v_buf  = (unsigned short*)(ws + (40u<<20));      // 8 MiB
  unsigned short* wv_out = norm_b;  // reuse: norm no longer needed once attn runs

  // 1. weights -> bf16
  cvt_w<<<(2048*1024/4 + 255)/256, 256, 0, stream>>>(w_qk, wqk_b, 2048*1024/4);
  cvt_w<<<(1024*1024/4 + 255)/256, 256, 0, stream>>>(w_v,  wv_b,  1024*1024/4);
  cvt_w<<<(1024*1024/4 + 255)/256, 256, 0, stream>>>(w_o,  wo_b,  1024*1024/4);
  // 2. LayerNorm (+pos)
  ln_posadd<<<MROWS, 256, 0, stream>>>(in_feats, pos, ln_g, ln_b, norm_b, posn_b);
  // 3. QK projection: [4096,2048] = posn @ w_qk^T
  gemm_bt<0><<<dim3(MROWS/128, 2048/128), 256, 0, stream>>>(posn_b, wqk_b, b_qk, nullptr,
                                                            qk_buf, MROWS, 2048, FDIM);
  // 4. V projection: [4096,1024] = norm @ w_v^T
  gemm_bt<0><<<dim3(MROWS/128, 1024/128), 256, 0, stream>>>(norm_b, wv_b, b_v, nullptr,
                                                            v_buf, MROWS, 1024, FDIM);
  // 5. attention
  attn<<<dim3(SEQ/64, NHEADS, BATCH), 256, 0, stream>>>(qk_buf, v_buf, wv_out);
  // 6. O projection + bias + residual -> fp32 out
  gemm_bt<1><<<dim3(MROWS/128, 1024/128), 256, 0, stream>>>(wv_out, wo_b, b_o, in_feats,
                                                            out, MROWS, 1024, FDIM);
}

// Round 3
// 268.816 us; speedup vs baseline: 1.0247x; 1.0247x over previous
//
#include <hip/hip_runtime.h>
#include <hip/hip_bf16.h>
#include <stdint.h>

// Problem constants (B=4, N=1024, F=1024, H=16, D=64)
#define FDIM 1024
#define NHEADS 16
#define HDIM 64
#define BATCH 4
#define SEQ 1024
#define MROWS (BATCH*SEQ)   // 4096

typedef short bf16x8 __attribute__((ext_vector_type(8)));
typedef float f32x4 __attribute__((ext_vector_type(4)));

__device__ inline unsigned short f2bf(float f){
  union { float f; uint32_t u; } v; v.f = f;
  uint32_t u = v.u;
  uint32_t r = (u + 0x7fffu + ((u >> 16) & 1u)) >> 16;
  return (unsigned short)r;
}

__device__ inline void gld_lds16(const void* g, void* l){
  __builtin_amdgcn_global_load_lds((const __attribute__((address_space(1))) uint32_t*)g,
                                   (__attribute__((address_space(3))) uint32_t*)l, 16, 0, 0);
}

// swizzled LDS b128 read of one 8-elem fragment row: tile is [64 rows][8 colgroups of 8 bf16],
// physical colgroup = logical colgroup ^ (row&7)
__device__ inline bf16x8 ldsw(const unsigned short* base, int row, int colgrp){
  return *(const bf16x8*)&base[row*64 + (((colgrp) ^ (row&7))<<3)];
}

// ---------------- weight fp32 -> bf16 ----------------
__global__ __launch_bounds__(256) void cvt_w(const float* __restrict__ src,
                                             unsigned short* __restrict__ dst, int n4){
  int i = blockIdx.x*256 + threadIdx.x;
  if (i < n4){
    float4 v = ((const float4*)src)[i];
    ushort4 o; o.x=f2bf(v.x); o.y=f2bf(v.y); o.z=f2bf(v.z); o.w=f2bf(v.w);
    ((ushort4*)dst)[i] = o;
  }
}

// ---------------- LayerNorm + pos add ----------------
__global__ __launch_bounds__(256) void ln_posadd(const float* __restrict__ x,
                                                 const float* __restrict__ pos,
                                                 const float* __restrict__ g,
                                                 const float* __restrict__ be,
                                                 unsigned short* __restrict__ normb,
                                                 unsigned short* __restrict__ posnb){
  int row = blockIdx.x, t = threadIdx.x;
  float4 v = ((const float4*)(x + (size_t)row*FDIM))[t];
  float s  = v.x+v.y+v.z+v.w;
  float sq = v.x*v.x+v.y*v.y+v.z*v.z+v.w*v.w;
  #pragma unroll
  for (int off=32; off>=1; off>>=1){ s += __shfl_down(s,off); sq += __shfl_down(sq,off); }
  __shared__ float red[8];
  int w=t>>6, lane=t&63;
  if (!lane){ red[w]=s; red[4+w]=sq; }
  __syncthreads();
  s  = red[0]+red[1]+red[2]+red[3];
  sq = red[4]+red[5]+red[6]+red[7];
  float mu  = s*(1.0f/FDIM);
  float var = sq*(1.0f/FDIM) - mu*mu;
  float rs  = rsqrtf(var + 1e-5f);
  float4 gg=((const float4*)g)[t], bb=((const float4*)be)[t];
  float4 pp=((const float4*)(pos + (size_t)row*FDIM))[t];
  float n0=(v.x-mu)*rs*gg.x+bb.x, n1=(v.y-mu)*rs*gg.y+bb.y;
  float n2=(v.z-mu)*rs*gg.z+bb.z, n3=(v.w-mu)*rs*gg.w+bb.w;
  ushort4 nb; nb.x=f2bf(n0); nb.y=f2bf(n1); nb.z=f2bf(n2); nb.w=f2bf(n3);
  ushort4 pb; pb.x=f2bf(n0+pp.x); pb.y=f2bf(n1+pp.y); pb.z=f2bf(n2+pp.z); pb.w=f2bf(n3+pp.w);
  ((ushort4*)(normb+(size_t)row*FDIM))[t]=nb;
  ((ushort4*)(posnb+(size_t)row*FDIM))[t]=pb;
}

// ---------------- GEMM: C[M,N] = A[M,K] @ W[N,K]^T + bias ----------------
// MODE 0: store bf16 into Cout. MODE 1: fp32 store of acc + bias + resid.
template<int MODE>
__global__ __launch_bounds__(256) void gemm_bt(const unsigned short* __restrict__ A,
                                               const unsigned short* __restrict__ Bw,
                                               const float* __restrict__ bias,
                                               const float* __restrict__ resid,
                                               void* __restrict__ Cout,
                                               int M, int Nout, int K){
  __shared__ unsigned short Als[128*32];
  __shared__ unsigned short Bls[128*32];
  int t = threadIdx.x, w = t>>6, lane = t&63;
  int m0 = blockIdx.x*128, n0 = blockIdx.y*128;
  int wm = (w>>1)*64, wn = (w&1)*64;
  int lrow = lane&15, lk = (lane>>4)*8, rg = lane>>4;
  f32x4 acc[4][4] = {};
  for (int k0=0; k0<K; k0+=32){
    #pragma unroll
    for (int i=0;i<2;i++){
      int c = t + i*256;
      gld_lds16(A  + (size_t)(m0 + (c>>2))*K + k0 + (c&3)*8, Als + c*8);
      gld_lds16(Bw + (size_t)(n0 + (c>>2))*K + k0 + (c&3)*8, Bls + c*8);
    }
    __syncthreads();
    bf16x8 a[4], b[4];
    #pragma unroll
    for (int i=0;i<4;i++){
      a[i] = *(const bf16x8*)&Als[(wm + i*16 + lrow)*32 + lk];
      b[i] = *(const bf16x8*)&Bls[(wn + i*16 + lrow)*32 + lk];
    }
    #pragma unroll
    for (int mi=0;mi<4;mi++)
      #pragma unroll
      for (int ni=0;ni<4;ni++)
        acc[mi][ni] = __builtin_amdgcn_mfma_f32_16x16x32_bf16(a[mi], b[ni], acc[mi][ni], 0,0,0);
    __syncthreads();
  }
  #pragma unroll
  for (int mi=0;mi<4;mi++){
    #pragma unroll
    for (int ni=0;ni<4;ni++){
      int n = n0 + wn + ni*16 + lrow;
      float bs = bias[n];
      #pragma unroll
      for (int r=0;r<4;r++){
        int m = m0 + wm + mi*16 + rg*4 + r;
        float vv = acc[mi][ni][r] + bs;
        size_t idx = (size_t)m*Nout + n;
        if (MODE==0) ((unsigned short*)Cout)[idx] = f2bf(vv);
        else         ((float*)Cout)[idx] = vv + resid[idx];
      }
    }
  }
}

// ---------------- Flash attention: block = (b, h, 64 q-rows) ----------------
// All four LDS tiles are [64][64] bf16 with XOR bank swizzle:
// physical 16B-colgroup = logical colgroup ^ (row&7).
__global__ __launch_bounds__(256) void attn(const unsigned short* __restrict__ qk,
                                            const unsigned short* __restrict__ vbuf,
                                            unsigned short* __restrict__ wvbuf){
  __shared__ unsigned short Qls[64*64];
  __shared__ unsigned short Kls[64*64];
  __shared__ unsigned short Vtls[64*64];   // transposed: [d][key]
  __shared__ unsigned short Pls[64*64];
  int t=threadIdx.x, w=t>>6, lane=t&63;
  int lrow=lane&15, lcg=lane>>4, rg=lane>>4;
  // XCD-chunked decode: consecutive logical wgids (same b,h) on one XCD
  int bid = blockIdx.x;
  int wgid = (bid&7)*128 + (bid>>3);
  int q0 = (wgid&15)*64, h = (wgid>>4)&15, b = wgid>>8;
  const size_t qs = 2*FDIM;
  // stage Q once (inverse-swizzled source -> linear LDS dest)
  #pragma unroll
  for (int i=0;i<2;i++){
    int c=t+i*256, row=c>>3, cg=(c&7)^(row&7);
    gld_lds16(qk + (size_t)(b*SEQ + q0 + row)*qs + h*HDIM + cg*8, Qls + c*8);
  }
  f32x4 o[4] = {};
  float m_run[4], l_run[4];
  #pragma unroll
  for (int r=0;r<4;r++){ m_run[r]=-1e30f; l_run[r]=0.f; }
  __syncthreads();
  bf16x8 qa[2];
  qa[0] = ldsw(Qls, w*16+lrow, 0*4 + lcg);
  qa[1] = ldsw(Qls, w*16+lrow, 1*4 + lcg);

  const float SCL = 0.125f * 1.44269504f;   // head-scale * log2(e)

  for (int kt=0; kt<16; ++kt){
    int key0 = kt*64;
    __syncthreads();  // previous iteration's LDS reads complete
    #pragma unroll
    for (int i=0;i<2;i++){
      int c=t+i*256, row=c>>3, cg=(c&7)^(row&7);
      gld_lds16(qk + (size_t)(b*SEQ + key0 + row)*qs + FDIM + h*HDIM + cg*8, Kls + c*8);
    }
    #pragma unroll
    for (int i=0;i<2;i++){
      int c=t+i*256;
      int key=c&63, d0=(c>>6)*8;
      bf16x8 vv = *(const bf16x8*)(vbuf + (size_t)(b*SEQ + key0 + key)*FDIM + h*HDIM + d0);
      #pragma unroll
      for (int j=0;j<8;j++)
        Vtls[(d0+j)*64 + ((((key>>3) ^ j))<<3) + (key&7)] = (unsigned short)vv[j];
    }
    __syncthreads();
    // S = Q K^T (per wave: 16 q-rows x 64 keys)
    f32x4 s[4] = {};
    #pragma unroll
    for (int kf=0; kf<2; kf++){
      #pragma unroll
      for (int ni=0;ni<4;ni++){
        bf16x8 kb = ldsw(Kls, ni*16+lrow, kf*4 + lcg);
        s[ni] = __builtin_amdgcn_mfma_f32_16x16x32_bf16(qa[kf], kb, s[ni], 0,0,0);
      }
    }
    // online softmax in exp2 domain; acc mapping: q_local = rg*4+r, key = ni*16 + lrow
    #pragma unroll
    for (int r=0;r<4;r++){
      float tm = fmaxf(fmaxf(s[0][r],s[1][r]), fmaxf(s[2][r],s[3][r])) * SCL;
      #pragma unroll
      for (int off=1; off<16; off<<=1) tm = fmaxf(tm, __shfl_xor(tm, off));
      float mn = fmaxf(m_run[r], tm);
      float sc = exp2f(m_run[r] - mn);
      float p[4]; float ts = 0.f;
      #pragma unroll
      for (int ni=0;ni<4;ni++){ p[ni] = exp2f(s[ni][r]*SCL - mn); ts += p[ni]; }
      #pragma unroll
      for (int off=1; off<16; off<<=1) ts += __shfl_xor(ts, off);
      l_run[r] = l_run[r]*sc + ts;
      m_run[r] = mn;
      #pragma unroll
      for (int nd=0;nd<4;nd++) o[nd][r] *= sc;
      int pr = w*16 + rg*4 + r;
      #pragma unroll
      for (int ni=0;ni<4;ni++)
        Pls[pr*64 + (((ni*2 + (lrow>>3)) ^ (pr&7))<<3) + (lrow&7)] = f2bf(p[ni]);
    }
    // O += P V   (P: [16 q x 64 key], V^T in LDS: [d][key])
    #pragma unroll
    for (int kf=0; kf<2; kf++){
      bf16x8 pa = ldsw(Pls, w*16+lrow, kf*4 + lcg);
      #pragma unroll
      for (int nd=0;nd<4;nd++){
        bf16x8 vb = ldsw(Vtls, nd*16+lrow, kf*4 + lcg);
        o[nd] = __builtin_amdgcn_mfma_f32_16x16x32_bf16(pa, vb, o[nd], 0,0,0);
      }
    }
  }
  // epilogue: divide by softmax denom, store bf16
  #pragma unroll
  for (int nd=0; nd<4; nd++){
    #pragma unroll
    for (int r=0;r<4;r++){
      float val = o[nd][r] / l_run[r];
      wvbuf[(size_t)(b*SEQ + q0 + w*16 + rg*4 + r)*FDIM + h*HDIM + nd*16 + lrow] = f2bf(val);
    }
  }
}

extern "C" void kernel_launch(void* const* d_in, const int* in_sizes, int n_in,
                              void* d_out, int out_size, void* d_ws, size_t ws_size,
                              hipStream_t stream) {
  const float* in_feats = (const float*)d_in[0];
  const float* pos      = (const float*)d_in[1];
  const float* ln_g     = (const float*)d_in[2];
  const float* ln_b     = (const float*)d_in[3];
  const float* w_qk     = (const float*)d_in[4];
  const float* b_qk     = (const float*)d_in[5];
  const float* w_v      = (const float*)d_in[6];
  const float* b_v      = (const float*)d_in[7];
  const float* w_o      = (const float*)d_in[8];
  const float* b_o      = (const float*)d_in[9];
  float* out = (float*)d_out;

  char* ws = (char*)d_ws;
  unsigned short* norm_b = (unsigned short*)(ws + 0);              // 8 MiB
  unsigned short* posn_b = (unsigned short*)(ws + (8u<<20));       // 8 MiB
  unsigned short* wqk_b  = (unsigned short*)(ws + (16u<<20));      // 4 MiB
  unsigned short* wv_b   = (unsigned short*)(ws + (20u<<20));      // 2 MiB
  unsigned short* wo_b   = (unsigned short*)(ws + (22u<<20));      // 2 MiB
  unsigned short* qk_buf = (unsigned short*)(ws + (24u<<20));      // 16 MiB
  unsigned short* v_buf  = (unsigned short*)(ws + (40u<<20));      // 8 MiB
  unsigned short* wv_out = norm_b;  // reuse: norm no longer needed once attn runs

  cvt_w<<<(2048*1024/4 + 255)/256, 256, 0, stream>>>(w_qk, wqk_b, 2048*1024/4);
  cvt_w<<<(1024*1024/4 + 255)/256, 256, 0, stream>>>(w_v,  wv_b,  1024*1024/4);
  cvt_w<<<(1024*1024/4 + 255)/256, 256, 0, stream>>>(w_o,  wo_b,  1024*1024/4);
  ln_posadd<<<MROWS, 256, 0, stream>>>(in_feats, pos, ln_g, ln_b, norm_b, posn_b);
  gemm_bt<0><<<dim3(MROWS/128, 2048/128), 256, 0, stream>>>(posn_b, wqk_b, b_qk, nullptr,
                                                            qk_buf, MROWS, 2048, FDIM);
  gemm_bt<0><<<dim3(MROWS/128, 1024/128), 256, 0, stream>>>(norm_b, wv_b, b_v, nullptr,
                                                            v_buf, MROWS, 1024, FDIM);
  attn<<<dim3(SEQ/64 * NHEADS * BATCH), 256, 0, stream>>>(qk_buf, v_buf, wv_out);
  gemm_bt<1><<<dim3(MROWS/128, 1024/128), 256, 0, stream>>>(wv_out, wo_b, b_o, in_feats,
                                                            out, MROWS, 1024, FDIM);
}

// Round 4
// 257.190 us; speedup vs baseline: 1.0711x; 1.0452x over previous
//
#include <hip/hip_runtime.h>
#include <hip/hip_bf16.h>
#include <stdint.h>

// Problem constants (B=4, N=1024, F=1024, H=16, D=64)
#define FDIM 1024
#define NHEADS 16
#define HDIM 64
#define BATCH 4
#define SEQ 1024
#define MROWS (BATCH*SEQ)   // 4096

typedef short bf16x8 __attribute__((ext_vector_type(8)));
typedef float f32x4 __attribute__((ext_vector_type(4)));

__device__ inline unsigned short f2bf(float f){
  union { float f; uint32_t u; } v; v.f = f;
  uint32_t u = v.u;
  uint32_t r = (u + 0x7fffu + ((u >> 16) & 1u)) >> 16;
  return (unsigned short)r;
}

__device__ inline void gld_lds16(const void* g, void* l){
  __builtin_amdgcn_global_load_lds((const __attribute__((address_space(1))) uint32_t*)g,
                                   (__attribute__((address_space(3))) uint32_t*)l, 16, 0, 0);
}

// swizzled LDS b128 read: tile [64 rows][8 colgroups of 8 bf16], phys cg = cg ^ (row&7)
__device__ inline bf16x8 ldsw(const unsigned short* base, int row, int colgrp){
  return *(const bf16x8*)&base[row*64 + (((colgrp) ^ (row&7))<<3)];
}

// DPP rotate-right by N within each 16-lane row (VALU pipe, not DS)
template<int N>
__device__ inline float dppRor(float x){
  int r = __builtin_amdgcn_update_dpp(0, __float_as_int(x), 0x120|N, 0xF, 0xF, true);
  return __int_as_float(r);
}
__device__ inline float rowMax16(float x){
  x = fmaxf(x, dppRor<1>(x)); x = fmaxf(x, dppRor<2>(x));
  x = fmaxf(x, dppRor<4>(x)); x = fmaxf(x, dppRor<8>(x));
  return x;
}
__device__ inline float rowSum16(float x){
  x += dppRor<1>(x); x += dppRor<2>(x); x += dppRor<4>(x); x += dppRor<8>(x);
  return x;
}

// ---------------- all three weights fp32 -> bf16, one launch ----------------
__global__ __launch_bounds__(256) void cvt_all(const float* __restrict__ wqk,
                                               const float* __restrict__ wv,
                                               const float* __restrict__ wo,
                                               unsigned short* __restrict__ oqk,
                                               unsigned short* __restrict__ ov,
                                               unsigned short* __restrict__ oo){
  int i = blockIdx.x*256 + threadIdx.x;   // in float4 units; total 1048576
  const float* src; unsigned short* dst; int j;
  if (i < 524288)      { src = wqk; dst = oqk; j = i; }
  else if (i < 786432) { src = wv;  dst = ov;  j = i - 524288; }
  else                 { src = wo;  dst = oo;  j = i - 786432; }
  float4 v = ((const float4*)src)[j];
  ushort4 o; o.x=f2bf(v.x); o.y=f2bf(v.y); o.z=f2bf(v.z); o.w=f2bf(v.w);
  ((ushort4*)dst)[j] = o;
}

// ---------------- LayerNorm + pos add ----------------
__global__ __launch_bounds__(256) void ln_posadd(const float* __restrict__ x,
                                                 const float* __restrict__ pos,
                                                 const float* __restrict__ g,
                                                 const float* __restrict__ be,
                                                 unsigned short* __restrict__ normb,
                                                 unsigned short* __restrict__ posnb){
  int row = blockIdx.x, t = threadIdx.x;
  float4 v = ((const float4*)(x + (size_t)row*FDIM))[t];
  float s  = v.x+v.y+v.z+v.w;
  float sq = v.x*v.x+v.y*v.y+v.z*v.z+v.w*v.w;
  #pragma unroll
  for (int off=32; off>=1; off>>=1){ s += __shfl_down(s,off); sq += __shfl_down(sq,off); }
  __shared__ float red[8];
  int w=t>>6, lane=t&63;
  if (!lane){ red[w]=s; red[4+w]=sq; }
  __syncthreads();
  s  = red[0]+red[1]+red[2]+red[3];
  sq = red[4]+red[5]+red[6]+red[7];
  float mu  = s*(1.0f/FDIM);
  float var = sq*(1.0f/FDIM) - mu*mu;
  float rs  = rsqrtf(var + 1e-5f);
  float4 gg=((const float4*)g)[t], bb=((const float4*)be)[t];
  float4 pp=((const float4*)(pos + (size_t)row*FDIM))[t];
  float n0=(v.x-mu)*rs*gg.x+bb.x, n1=(v.y-mu)*rs*gg.y+bb.y;
  float n2=(v.z-mu)*rs*gg.z+bb.z, n3=(v.w-mu)*rs*gg.w+bb.w;
  ushort4 nb; nb.x=f2bf(n0); nb.y=f2bf(n1); nb.z=f2bf(n2); nb.w=f2bf(n3);
  ushort4 pb; pb.x=f2bf(n0+pp.x); pb.y=f2bf(n1+pp.y); pb.z=f2bf(n2+pp.z); pb.w=f2bf(n3+pp.w);
  ((ushort4*)(normb+(size_t)row*FDIM))[t]=nb;
  ((ushort4*)(posnb+(size_t)row*FDIM))[t]=pb;
}

// ---------------- GEMM: C[M,N] = A[M,K] @ W[N,K]^T + bias ----------------
// MODE 0: bf16 store, bias[n]. MODE 1: fp32 store + bias[n] + resid.
// MODE 2: bf16 store, bias[m] (used to produce V^T = Wv @ norm^T).
template<int MODE>
__global__ __launch_bounds__(256) void gemm_bt(const unsigned short* __restrict__ A,
                                               const unsigned short* __restrict__ Bw,
                                               const float* __restrict__ bias,
                                               const float* __restrict__ resid,
                                               void* __restrict__ Cout,
                                               int M, int Nout, int K){
  __shared__ unsigned short Als[128*32];
  __shared__ unsigned short Bls[128*32];
  int t = threadIdx.x, w = t>>6, lane = t&63;
  int m0 = blockIdx.x*128, n0 = blockIdx.y*128;
  int wm = (w>>1)*64, wn = (w&1)*64;
  int lrow = lane&15, lk = (lane>>4)*8, rg = lane>>4;
  f32x4 acc[4][4] = {};
  for (int k0=0; k0<K; k0+=32){
    #pragma unroll
    for (int i=0;i<2;i++){
      int c = t + i*256;
      gld_lds16(A  + (size_t)(m0 + (c>>2))*K + k0 + (c&3)*8, Als + c*8);
      gld_lds16(Bw + (size_t)(n0 + (c>>2))*K + k0 + (c&3)*8, Bls + c*8);
    }
    __syncthreads();
    bf16x8 a[4], b[4];
    #pragma unroll
    for (int i=0;i<4;i++){
      a[i] = *(const bf16x8*)&Als[(wm + i*16 + lrow)*32 + lk];
      b[i] = *(const bf16x8*)&Bls[(wn + i*16 + lrow)*32 + lk];
    }
    #pragma unroll
    for (int mi=0;mi<4;mi++)
      #pragma unroll
      for (int ni=0;ni<4;ni++)
        acc[mi][ni] = __builtin_amdgcn_mfma_f32_16x16x32_bf16(a[mi], b[ni], acc[mi][ni], 0,0,0);
    __syncthreads();
  }
  #pragma unroll
  for (int mi=0;mi<4;mi++){
    #pragma unroll
    for (int ni=0;ni<4;ni++){
      int n = n0 + wn + ni*16 + lrow;
      float bs = (MODE==2) ? 0.f : bias[n];
      #pragma unroll
      for (int r=0;r<4;r++){
        int m = m0 + wm + mi*16 + rg*4 + r;
        float vv = acc[mi][ni][r] + ((MODE==2) ? bias[m] : bs);
        size_t idx = (size_t)m*Nout + n;
        if (MODE==1) ((float*)Cout)[idx] = vv + resid[idx];
        else         ((unsigned short*)Cout)[idx] = f2bf(vv);
      }
    }
  }
}

// ---------------- Flash attention: block = (b, h, 64 q-rows) ----------------
// K/V^T double-buffered, one barrier per kt; softmax reduces on VALU via DPP.
// vt layout: [F=1024 feat rows][4096 seq cols] so V^T tile stages like K.
__global__ __launch_bounds__(256) void attn(const unsigned short* __restrict__ qk,
                                            const unsigned short* __restrict__ vt,
                                            unsigned short* __restrict__ wvbuf){
  __shared__ unsigned short Qls[64*64];
  __shared__ unsigned short Kls[2][64*64];
  __shared__ unsigned short Vtls[2][64*64];   // [d][key]
  __shared__ unsigned short Pls[64*64];
  int t=threadIdx.x, w=t>>6, lane=t&63;
  int lrow=lane&15, lcg=lane>>4, rg=lane>>4;
  // XCD-chunked decode: consecutive logical wgids (same b,h) on one XCD
  int bid = blockIdx.x;
  int wgid = (bid&7)*128 + (bid>>3);
  int q0 = (wgid&15)*64, h = (wgid>>4)&15, b = wgid>>8;
  const size_t qs = 2*FDIM;

  // prologue: stage Q, K0, Vt0 (inverse-swizzled source -> linear LDS dest)
  #pragma unroll
  for (int i=0;i<2;i++){
    int c=t+i*256, row=c>>3, cg=(c&7)^(row&7);
    gld_lds16(qk + (size_t)(b*SEQ + q0 + row)*qs + h*HDIM + cg*8, Qls + c*8);
    gld_lds16(qk + (size_t)(b*SEQ + row)*qs + FDIM + h*HDIM + cg*8, Kls[0] + c*8);
    gld_lds16(vt + (size_t)(h*HDIM + row)*MROWS + b*SEQ + cg*8, Vtls[0] + c*8);
  }
  f32x4 o[4] = {};
  float m_run[4], l_run[4];
  #pragma unroll
  for (int r=0;r<4;r++){ m_run[r]=-1e30f; l_run[r]=0.f; }
  __syncthreads();
  bf16x8 qa[2];
  qa[0] = ldsw(Qls, w*16+lrow, 0*4 + lcg);
  qa[1] = ldsw(Qls, w*16+lrow, 1*4 + lcg);

  const float SCL = 0.125f * 1.44269504f;   // head-scale * log2(e)
  int cur = 0;

  for (int kt=0; kt<16; ++kt){
    // issue next tile's staging first (hides under compute; barrier drains it)
    if (kt < 15){
      int key1 = (kt+1)*64;
      #pragma unroll
      for (int i=0;i<2;i++){
        int c=t+i*256, row=c>>3, cg=(c&7)^(row&7);
        gld_lds16(qk + (size_t)(b*SEQ + key1 + row)*qs + FDIM + h*HDIM + cg*8, Kls[cur^1] + c*8);
        gld_lds16(vt + (size_t)(h*HDIM + row)*MROWS + b*SEQ + key1 + cg*8, Vtls[cur^1] + c*8);
      }
    }
    // S = Q K^T (per wave: 16 q-rows x 64 keys)
    f32x4 s[4] = {};
    #pragma unroll
    for (int kf=0; kf<2; kf++){
      #pragma unroll
      for (int ni=0;ni<4;ni++){
        bf16x8 kb = ldsw(Kls[cur], ni*16+lrow, kf*4 + lcg);
        s[ni] = __builtin_amdgcn_mfma_f32_16x16x32_bf16(qa[kf], kb, s[ni], 0,0,0);
      }
    }
    // online softmax (exp2 domain); q_local = rg*4+r, key = ni*16 + lrow
    #pragma unroll
    for (int r=0;r<4;r++){
      float tm = fmaxf(fmaxf(s[0][r],s[1][r]), fmaxf(s[2][r],s[3][r])) * SCL;
      tm = rowMax16(tm);
      float mn = fmaxf(m_run[r], tm);
      float sc = exp2f(m_run[r] - mn);
      float p[4]; float ts = 0.f;
      #pragma unroll
      for (int ni=0;ni<4;ni++){ p[ni] = exp2f(s[ni][r]*SCL - mn); ts += p[ni]; }
      ts = rowSum16(ts);
      l_run[r] = l_run[r]*sc + ts;
      m_run[r] = mn;
      #pragma unroll
      for (int nd=0;nd<4;nd++) o[nd][r] *= sc;
      int pr = w*16 + rg*4 + r;
      #pragma unroll
      for (int ni=0;ni<4;ni++)
        Pls[pr*64 + (((ni*2 + (lrow>>3)) ^ (pr&7))<<3) + (lrow&7)] = f2bf(p[ni]);
    }
    // O += P V   (P: [16 q x 64 key], V^T in LDS: [d][key]) — same-wave P rows only
    #pragma unroll
    for (int kf=0; kf<2; kf++){
      bf16x8 pa = ldsw(Pls, w*16+lrow, kf*4 + lcg);
      #pragma unroll
      for (int nd=0;nd<4;nd++){
        bf16x8 vb = ldsw(Vtls[cur], nd*16+lrow, kf*4 + lcg);
        o[nd] = __builtin_amdgcn_mfma_f32_16x16x32_bf16(pa, vb, o[nd], 0,0,0);
      }
    }
    __syncthreads();   // drains staged loads + orders buffer reuse
    cur ^= 1;
  }
  // epilogue: divide by softmax denom, store bf16
  #pragma unroll
  for (int nd=0; nd<4; nd++){
    #pragma unroll
    for (int r=0;r<4;r++){
      float val = o[nd][r] / l_run[r];
      wvbuf[(size_t)(b*SEQ + q0 + w*16 + rg*4 + r)*FDIM + h*HDIM + nd*16 + lrow] = f2bf(val);
    }
  }
}

extern "C" void kernel_launch(void* const* d_in, const int* in_sizes, int n_in,
                              void* d_out, int out_size, void* d_ws, size_t ws_size,
                              hipStream_t stream) {
  const float* in_feats = (const float*)d_in[0];
  const float* pos      = (const float*)d_in[1];
  const float* ln_g     = (const float*)d_in[2];
  const float* ln_b     = (const float*)d_in[3];
  const float* w_qk     = (const float*)d_in[4];
  const float* b_qk     = (const float*)d_in[5];
  const float* w_v      = (const float*)d_in[6];
  const float* b_v      = (const float*)d_in[7];
  const float* w_o      = (const float*)d_in[8];
  const float* b_o      = (const float*)d_in[9];
  float* out = (float*)d_out;

  char* ws = (char*)d_ws;
  unsigned short* norm_b = (unsigned short*)(ws + 0);              // 8 MiB
  unsigned short* posn_b = (unsigned short*)(ws + (8u<<20));       // 8 MiB
  unsigned short* wqk_b  = (unsigned short*)(ws + (16u<<20));      // 4 MiB
  unsigned short* wv_b   = (unsigned short*)(ws + (20u<<20));      // 2 MiB
  unsigned short* wo_b   = (unsigned short*)(ws + (22u<<20));      // 2 MiB
  unsigned short* qk_buf = (unsigned short*)(ws + (24u<<20));      // 16 MiB
  unsigned short* vt_buf = (unsigned short*)(ws + (40u<<20));      // 8 MiB  [1024][4096]
  unsigned short* wv_out = norm_b;  // reuse: norm no longer needed once attn runs

  cvt_all<<<4096, 256, 0, stream>>>(w_qk, w_v, w_o, wqk_b, wv_b, wo_b);
  ln_posadd<<<MROWS, 256, 0, stream>>>(in_feats, pos, ln_g, ln_b, norm_b, posn_b);
  // QK projection: [4096,2048] = posn @ w_qk^T
  gemm_bt<0><<<dim3(MROWS/128, 2048/128), 256, 0, stream>>>(posn_b, wqk_b, b_qk, nullptr,
                                                            qk_buf, MROWS, 2048, FDIM);
  // V^T projection: [1024,4096] = w_v @ norm^T  (bias per output row)
  gemm_bt<2><<<dim3(FDIM/128, MROWS/128), 256, 0, stream>>>(wv_b, norm_b, b_v, nullptr,
                                                            vt_buf, FDIM, MROWS, FDIM);
  attn<<<dim3(SEQ/64 * NHEADS * BATCH), 256, 0, stream>>>(qk_buf, vt_buf, wv_out);
  // O projection + bias + residual -> fp32 out
  gemm_bt<1><<<dim3(MROWS/128, 1024/128), 256, 0, stream>>>(wv_out, wo_b, b_o, in_feats,
                                                            out, MROWS, 1024, FDIM);
}